// Round 5
// baseline (61.990 us; speedup 1.0000x reference)
//
#include <hip/hip_runtime.h>
#include <math.h>

#define BB 2
#define NAT 2048
#define NTOK 256

struct WS {
  // pair-phase f64 accumulators (zeroed by k_atom)
  double bond_num[BB];
  double bond_den[BB];
  double cem[BB];
  double cm[BB];
  // per-atom derived
  float wA[BB*NAT];
  float nucA[BB*NAT];
  float ligA[BB*NAT];
  // packed column data: px = {x,y,z, bitcast(tok | polbit<<8)}, pg = {gx,gy,gz, mask}
  float4 px[BB*NAT];
  float4 pg[BB*NAT];
};

// ---------------- K1: per-atom tables + packing (one wave per atom) ----------------
__global__ __launch_bounds__(256) void k_atom(
    const float* __restrict__ x, const float* __restrict__ xgt,
    const float* __restrict__ mask, const float* __restrict__ A,
    const float* __restrict__ poly, const float* __restrict__ lig,
    const float* __restrict__ dna, const float* __restrict__ rna,
    WS* __restrict__ ws) {
  int tid = threadIdx.x;
  int gid = blockIdx.x * 4 + (tid >> 6);   // atom index, 0..BB*NAT-1
  int lane = tid & 63;
  int b = gid >> 11;
  float4 v = ((const float4*)(A + (size_t)gid * NTOK))[lane];
  float s = v.x * (float)(4*lane) + v.y * (float)(4*lane+1)
          + v.z * (float)(4*lane+2) + v.w * (float)(4*lane+3);
  for (int off = 32; off; off >>= 1) s += __shfl_xor(s, off);
  if (lane == 0) {
    int t = (int)(s + 0.5f);
    float d  = dna[b*NTOK + t], r = rna[b*NTOK + t];
    float li = lig[b*NTOK + t], po = poly[b*NTOK + t];
    float m  = mask[gid];
    ws->wA[gid]   = 1.0f + 5.0f*d + 5.0f*r + 10.0f*li;
    ws->nucA[gid] = d + r;
    ws->ligA[gid] = li;
    int meta = t | ((po != 0.0f) ? 256 : 0);
    const float* xp = x   + (size_t)gid * 3;
    const float* gp = xgt + (size_t)gid * 3;
    ws->px[gid] = make_float4(xp[0], xp[1], xp[2], __int_as_float(meta));
    ws->pg[gid] = make_float4(gp[0], gp[1], gp[2], m);
  }
  if (blockIdx.x == 0 && tid < 8) {  // zero pair accumulators (K2 runs after K1)
    ((double*)ws)[tid] = 0.0;
  }
}

// ---------------- K2: pair sums, LDS-staged columns, one wave per row ----------------
__global__ __launch_bounds__(256) void k_pair(const float* __restrict__ tb,
                                              WS* __restrict__ ws) {
  int tid = threadIdx.x, lane = tid & 63, wv = tid >> 6, blk = blockIdx.x;
  int gid = blk * 4 + wv;              // row atom index (block never straddles batch)
  int b = gid >> 11;
  int a = gid & (NAT - 1);
  const float4* __restrict__ pxb = ws->px + (size_t)b * NAT;
  const float4* __restrict__ pgb = ws->pg + (size_t)b * NAT;
  float4 pa = pxb[a];
  float4 ga = pgb[a];
  float ma = ga.w;
  float nuca = ws->nucA[gid];
  float lm = ws->ligA[gid] * ma;       // row-constant bond gate
  bool dob = (lm != 0.0f);
  float thresh = (nuca > 0.5f) ? 30.0f : 15.0f;
  int ta = __float_as_int(pa.w) & 255;
  const float* __restrict__ tbrow = tb + ((size_t)b * NTOK + ta) * NTOK;

  const float K1 = 0.60653066f;   // e^-0.5
  const float K2 = 0.36787944f;   // e^-1
  const float K3 = 0.13533528f;   // e^-2
  const float K4 = 0.018315639f;  // e^-4

  __shared__ float4 spx[256];
  __shared__ float4 spg[256];

  float bnum = 0.f, bden = 0.f, cemv = 0.f, cmv = 0.f;
  for (int t = 0; t < NAT / 256; t++) {
    __syncthreads();
    spx[tid] = pxb[t*256 + tid];
    spg[tid] = pgb[t*256 + tid];
    __syncthreads();
    #pragma unroll
    for (int k = 0; k < 4; k++) {
      int cl = lane + 64*k;
      int c = t*256 + cl;
      float4 pc = spx[cl];
      float4 gc = spg[cl];
      float d0 = pa.x-pc.x, d1 = pa.y-pc.y, d2 = pa.z-pc.z;
      float dxv = sqrtf(d0*d0 + d1*d1 + d2*d2);
      float e0 = ga.x-gc.x, e1 = ga.y-gc.y, e2 = ga.z-gc.z;
      float dgv = sqrtf(e0*e0 + e1*e1 + e2*e2);
      float diff = dxv - dgv;
      if (dob) {
        int meta = __float_as_int(pc.w);
        float tbv = tbrow[meta & 255];
        float bm = ((meta & 256) ? tbv : 0.0f) * gc.w;
        bnum += diff * diff * bm;
        bden += bm;
      }
      float dd = fabsf(diff);
      float E = __expf(dd);
      float e = __builtin_amdgcn_rcpf(1.0f + E*K1) + __builtin_amdgcn_rcpf(1.0f + E*K2)
              + __builtin_amdgcn_rcpf(1.0f + E*K3) + __builtin_amdgcn_rcpf(1.0f + E*K4);
      float pml = ((c == a) || (dgv >= thresh)) ? 0.0f : gc.w;  // ma factored out
      cemv += e * pml;
      cmv  += pml;
    }
  }

  float vals[4] = { lm * bnum, lm * bden, 0.25f * ma * cemv, ma * cmv };
  for (int k = 0; k < 4; k++)
    for (int off = 32; off; off >>= 1) vals[k] += __shfl_xor(vals[k], off);
  __shared__ double part[4][4];
  if (lane == 0)
    for (int k = 0; k < 4; k++) part[wv][k] = (double)vals[k];
  __syncthreads();
  if (tid < 4) {  // all 4 rows of this block belong to batch b
    int k = tid;
    double s = part[0][k] + part[1][k] + part[2][k] + part[3][k];
    double* dst = (k == 0) ? &ws->bond_num[b] : (k == 1) ? &ws->bond_den[b]
                : (k == 2) ? &ws->cem[b]      : &ws->cm[b];
    atomicAdd(dst, s);
  }
}

// ---------------- K3: moments + SVD + MSE + combine, one block ----------------
__device__ void svd3(const double* red, float* Rf, float* muf, float* mugf) {
  double swm = red[1];
  double mug[3] = { red[2]/swm, red[3]/swm, red[4]/swm };  // mean x
  double mu[3]  = { red[5]/swm, red[6]/swm, red[7]/swm };  // mean x_gt
  double H[3][3];
  for (int i = 0; i < 3; i++)
    for (int j = 0; j < 3; j++)
      H[i][j] = red[8 + 3*i + j] - swm * mug[i] * mu[j];
  double Km[3][3];
  for (int i = 0; i < 3; i++)
    for (int j = 0; j < 3; j++)
      Km[i][j] = H[0][i]*H[0][j] + H[1][i]*H[1][j] + H[2][i]*H[2][j];
  double V[3][3] = {{1,0,0},{0,1,0},{0,0,1}};
  for (int sweep = 0; sweep < 15; sweep++) {
    double off2 = Km[0][1]*Km[0][1] + Km[0][2]*Km[0][2] + Km[1][2]*Km[1][2];
    double dia2 = Km[0][0]*Km[0][0] + Km[1][1]*Km[1][1] + Km[2][2]*Km[2][2];
    if (off2 < 1e-26 * dia2 + 1e-300) break;
    for (int p = 0; p < 2; p++) {
      for (int q = p + 1; q < 3; q++) {
        double apq = Km[p][q];
        if (fabs(apq) < 1e-300) continue;
        double theta = (Km[q][q] - Km[p][p]) / (2.0 * apq);
        double t = 1.0 / (fabs(theta) + sqrt(theta*theta + 1.0));
        if (theta < 0) t = -t;
        double c = 1.0 / sqrt(t*t + 1.0), sn = t * c;
        for (int k = 0; k < 3; k++) {
          double akp = Km[k][p], akq = Km[k][q];
          Km[k][p] = c*akp - sn*akq;
          Km[k][q] = sn*akp + c*akq;
        }
        for (int k = 0; k < 3; k++) {
          double apk = Km[p][k], aqk = Km[q][k];
          Km[p][k] = c*apk - sn*aqk;
          Km[q][k] = sn*apk + c*aqk;
        }
        for (int k = 0; k < 3; k++) {
          double vkp = V[k][p], vkq = V[k][q];
          V[k][p] = c*vkp - sn*vkq;
          V[k][q] = sn*vkp + c*vkq;
        }
      }
    }
  }
  double ev[3] = { Km[0][0], Km[1][1], Km[2][2] };
  int id[3] = {0, 1, 2};
  for (int i = 0; i < 2; i++)
    for (int j = i + 1; j < 3; j++)
      if (ev[id[j]] > ev[id[i]]) { int tmp = id[i]; id[i] = id[j]; id[j] = tmp; }
  double Uc[3][3], Vc[3][3], S[3];
  for (int k = 0; k < 3; k++) {
    int e = id[k];
    double v0 = V[0][e], v1 = V[1][e], v2 = V[2][e];
    Vc[k][0] = v0; Vc[k][1] = v1; Vc[k][2] = v2;
    double u0 = H[0][0]*v0 + H[0][1]*v1 + H[0][2]*v2;
    double u1 = H[1][0]*v0 + H[1][1]*v1 + H[1][2]*v2;
    double u2 = H[2][0]*v0 + H[2][1]*v1 + H[2][2]*v2;
    double nrm = sqrt(u0*u0 + u1*u1 + u2*u2);
    S[k] = nrm;
    if (nrm > 1e-12) { u0 /= nrm; u1 /= nrm; u2 /= nrm; }
    Uc[k][0] = u0; Uc[k][1] = u1; Uc[k][2] = u2;
  }
  if (S[2] <= 1e-12 * (S[0] > 0 ? S[0] : 1.0)) {
    Uc[2][0] = Uc[0][1]*Uc[1][2] - Uc[0][2]*Uc[1][1];
    Uc[2][1] = Uc[0][2]*Uc[1][0] - Uc[0][0]*Uc[1][2];
    Uc[2][2] = Uc[0][0]*Uc[1][1] - Uc[0][1]*Uc[1][0];
  }
  double detU = Uc[0][0]*(Uc[1][1]*Uc[2][2]-Uc[1][2]*Uc[2][1])
              - Uc[1][0]*(Uc[0][1]*Uc[2][2]-Uc[0][2]*Uc[2][1])
              + Uc[2][0]*(Uc[0][1]*Uc[1][2]-Uc[0][2]*Uc[1][1]);
  double detV = Vc[0][0]*(Vc[1][1]*Vc[2][2]-Vc[1][2]*Vc[2][1])
              - Vc[1][0]*(Vc[0][1]*Vc[2][2]-Vc[0][2]*Vc[2][1])
              + Vc[2][0]*(Vc[0][1]*Vc[1][2]-Vc[0][2]*Vc[1][1]);
  double dsign = (detU * detV < 0.0) ? -1.0 : 1.0;
  for (int i = 0; i < 3; i++)
    for (int j = 0; j < 3; j++)
      Rf[3*i+j] = (float)(Uc[0][i]*Vc[0][j] + Uc[1][i]*Vc[1][j] + dsign*Uc[2][i]*Vc[2][j]);
  for (int i = 0; i < 3; i++) {
    muf[i]  = (float)mu[i];
    mugf[i] = (float)mug[i];
  }
}

__global__ __launch_bounds__(256) void k_finale(const WS* __restrict__ ws,
                                                float* __restrict__ out) {
  int tid = threadIdx.x, lane = tid & 63, wv = tid >> 6;
  __shared__ double sred[BB][17];
  __shared__ float sR[BB][9], smu[BB][3], smug[BB][3];
  __shared__ double part[4][17];

  // ---- moments, per batch ----
  for (int b = 0; b < BB; b++) {
    double acc[17];
    for (int k = 0; k < 17; k++) acc[k] = 0.0;
    for (int a = tid; a < NAT; a += 256) {
      int gid = b * NAT + a;
      float4 p = ws->px[gid];
      float4 g = ws->pg[gid];
      float m = g.w;
      if (m == 0.0f) continue;
      double wm = (double)(ws->wA[gid] * m);
      double x0 = p.x, x1 = p.y, x2 = p.z;
      double g0 = g.x, g1 = g.y, g2 = g.z;
      acc[0] += (double)m;
      acc[1] += wm;
      acc[2] += wm*x0; acc[3] += wm*x1; acc[4] += wm*x2;
      acc[5] += wm*g0; acc[6] += wm*g1; acc[7] += wm*g2;
      acc[8]  += wm*x0*g0; acc[9]  += wm*x0*g1; acc[10] += wm*x0*g2;
      acc[11] += wm*x1*g0; acc[12] += wm*x1*g1; acc[13] += wm*x1*g2;
      acc[14] += wm*x2*g0; acc[15] += wm*x2*g1; acc[16] += wm*x2*g2;
    }
    for (int k = 0; k < 17; k++)
      for (int off = 32; off; off >>= 1) acc[k] += __shfl_xor(acc[k], off);
    if (lane == 0)
      for (int k = 0; k < 17; k++) part[wv][k] = acc[k];
    __syncthreads();
    if (tid < 17)
      sred[b][tid] = part[0][tid] + part[1][tid] + part[2][tid] + part[3][tid];
    __syncthreads();
  }

  // ---- SVD: threads 0 and 1 in parallel, one batch each ----
  if (tid < BB) svd3(sred[tid], sR[tid], smu[tid], smug[tid]);
  __syncthreads();

  // ---- weighted MSE numerator (global sum over both batches) ----
  double msea = 0.0;
  for (int gid = tid; gid < BB*NAT; gid += 256) {
    int b = gid >> 11;
    float4 pa = ws->px[gid];
    float4 ga = ws->pg[gid];
    float ma = ga.w;
    if (ma == 0.0f) continue;
    const float* R = sR[b];
    float c0 = ga.x - smu[b][0], c1 = ga.y - smu[b][1], c2 = ga.z - smu[b][2];
    float a0 = R[0]*c0 + R[1]*c1 + R[2]*c2 + smug[b][0];
    float a1 = R[3]*c0 + R[4]*c1 + R[5]*c2 + smug[b][1];
    float a2 = R[6]*c0 + R[7]*c1 + R[8]*c2 + smug[b][2];
    float q0 = pa.x - a0, q1 = pa.y - a1, q2 = pa.z - a2;
    msea += (double)(ws->wA[gid] * ma * (q0*q0 + q1*q1 + q2*q2));
  }
  for (int off = 32; off; off >>= 1) msea += __shfl_xor(msea, off);
  __shared__ double mpart[4];
  if (lane == 0) mpart[wv] = msea;
  __syncthreads();

  // ---- combine ----
  if (tid == 0) {
    double mse_num = mpart[0] + mpart[1] + mpart[2] + mpart[3];
    const double wt = (4.0*4.0 + 16.0*16.0) / ((4.0+16.0)*(4.0+16.0));  // 0.68
    double lsum = 0.0;
    for (int b = 0; b < BB; b++) {
      double lmse  = mse_num / (3.0 * sred[b][0]);
      double lbond = ws->bond_num[b] / ws->bond_den[b];
      double lddt  = ws->cem[b] / ws->cm[b];
      lsum += wt * (lmse + lbond) + (1.0 - lddt);
    }
    out[0] = (float)(lsum / BB);
  }
}

extern "C" void kernel_launch(void* const* d_in, const int* in_sizes, int n_in,
                              void* d_out, int out_size, void* d_ws, size_t ws_size,
                              hipStream_t stream) {
  const float* x    = (const float*)d_in[0];
  const float* xgt  = (const float*)d_in[1];
  const float* mask = (const float*)d_in[2];
  const float* A    = (const float*)d_in[3];
  const float* tb   = (const float*)d_in[4];
  const float* poly = (const float*)d_in[5];
  const float* lig  = (const float*)d_in[6];
  const float* dna  = (const float*)d_in[7];
  const float* rna  = (const float*)d_in[8];
  WS* ws = (WS*)d_ws;
  float* out = (float*)d_out;

  k_atom<<<BB * NAT / 4, 256, 0, stream>>>(x, xgt, mask, A, poly, lig, dna, rna, ws);
  k_pair<<<BB * (NAT / 4), 256, 0, stream>>>(tb, ws);
  k_finale<<<1, 256, 0, stream>>>(ws, out);
}